// Round 1
// baseline (98.354 us; speedup 1.0000x reference)
//
#include <hip/hip_runtime.h>
#include <stdint.h>

#define B_SIZE        262144
#define NUM_CLASSES   1000
#define CODE_LEN      512
#define N_ELEMS       (NUM_CLASSES * CODE_LEN)   // 512000 floats
#define PACKED_WORDS  (NUM_CLASSES * 16)         // 16000 uint32 = 62.5 KB
#define CHUNKS        (NUM_CLASSES * 4)          // 4000 uint4 chunks
#define BLOCKS        256
#define THREADS       512                        // 8 waves/block -> 8 waves/CU
#define SAMPLES_PER_BLOCK (B_SIZE / BLOCKS)      // 1024 -> 2 per thread

// ws layout (bytes):
//   [0]      u32 partials[BLOCKS], one per 128B line (stride 32 u32)
//   [32768]  u32 pack-flags[BLOCKS], one per 128B line
//   [65536]  packed codebook, 16000 u32
#define WS_PART_OFF    0
#define WS_FLAG_OFF    32768
#define WS_PACKED_OFF  65536
#define LINE_STRIDE    32             // u32 elements = 128 B
#define PUB_MARKER     0x40000000u    // bit30: poison 0xAAAAAAAA has bit30=0

// Single fused kernel (saves one dispatch + kernel->kernel gap vs the
// previous pack+hamming pair):
//   phase 1: distributed ballot-pack, each block packs 1/256 of the table
//   phase 2: poison-proof flag barrier (atomics for flags, __threadfence
//            wb/inv for the plain-stored table data crossing XCD L2s)
//   phase 3: stage packed table -> LDS (bank-swizzled)
//   phase 4: 2 samples/thread, 16 LDS gathers issued before popcounts
//   phase 5: block reduce -> per-block 128B-line publish -> block 0 collects
// Deadlock-safe without cooperative launch: 64 KB LDS + 512 thr => 2
// blocks/CU capacity, so total capacity (512) >= grid (256): every WG is
// resident before any flag-wait can block.
__global__ __launch_bounds__(THREADS) void fused_hamming_kernel(
        const int* __restrict__ output,
        const int* __restrict__ target,
        const float* __restrict__ codebook,
        uint32_t* __restrict__ packed,
        unsigned int* __restrict__ pflags,
        unsigned int* __restrict__ partials,
        float* __restrict__ out) {
    __shared__ uint4 lds[CHUNKS];               // 64000 B
    __shared__ unsigned int wsum[THREADS / 64]; // 8 waves

    const int tid = threadIdx.x;

    // Prefetch this thread's 4 indices: loads issue now, complete while the
    // pack phase runs.
    int base = blockIdx.x * SAMPLES_PER_BLOCK + tid;
    int o0 = output[base],           t0 = target[base];
    int o1 = output[base + THREADS], t1 = target[base + THREADS];

    // ---- phase 1: distributed pack (grid-strided ballot) ----
    // e = it*131072 + blk*512 + tid; guard is wave-uniform (512000 = 232*512
    // + 3*131072, so every wave is fully active or fully inactive).
    #pragma unroll
    for (int it = 0; it < 4; it++) {
        int e = it * (BLOCKS * THREADS) + blockIdx.x * THREADS + tid;
        if (e < N_ELEMS) {
            float x = codebook[e];
            unsigned long long m = __ballot(x > 0.5f);
            if ((tid & 31) == 0)
                packed[e >> 5] = (uint32_t)(m >> (tid & 32));
        }
    }
    // Publish: syncthreads drains every wave's vmcnt (stores at least in this
    // XCD's L2); thread 0's threadfence writes the L2 back to the coherence
    // point; then a device-scope atomic sets the bit30-marker flag.
    __syncthreads();
    if (tid == 0) {
        __threadfence();
        atomicExch(&pflags[blockIdx.x * LINE_STRIDE], PUB_MARKER);
    }

    // ---- phase 2: wait for all 256 pack slices ----
    // Contention-free: thread i spins on its OWN 128B line via device-scope
    // atomic RMW (poison-proof: poison lacks bit30).
    if (tid < BLOCKS) {
        while (!(atomicAdd(&pflags[tid * LINE_STRIDE], 0u) & PUB_MARKER)) {}
    }
    __syncthreads();
    __threadfence();   // invalidate L1/L2 so plain loads below see the table

    // ---- phase 3: stage packed table -> LDS with bank swizzle ----
    // chunk k of row r stored at lds[4r + ((k + (r>>2)) & 3)]
    const uint4* pk4 = (const uint4*)packed;
    #pragma unroll
    for (int it = 0; it < 8; it++) {
        int g = tid + THREADS * it;
        if (g < CHUNKS) {
            int r = g >> 2, k = g & 3;
            lds[(r << 2) + ((k + (r >> 2)) & 3)] = pk4[g];
        }
    }
    __syncthreads();

    // ---- phase 4: 2 samples/thread, all 16 gathers issued before popc ----
    unsigned int sum = 0;
    {
        uint4 ao[4], at[4], bo[4], bt[4];
        int so0 = (o0 >> 2) & 3, st0 = (t0 >> 2) & 3;
        int so1 = (o1 >> 2) & 3, st1 = (t1 >> 2) & 3;
        #pragma unroll
        for (int k = 0; k < 4; k++) ao[k] = lds[(o0 << 2) + ((k + so0) & 3)];
        #pragma unroll
        for (int k = 0; k < 4; k++) at[k] = lds[(t0 << 2) + ((k + st0) & 3)];
        #pragma unroll
        for (int k = 0; k < 4; k++) bo[k] = lds[(o1 << 2) + ((k + so1) & 3)];
        #pragma unroll
        for (int k = 0; k < 4; k++) bt[k] = lds[(t1 << 2) + ((k + st1) & 3)];

        #pragma unroll
        for (int k = 0; k < 4; k++) {
            sum += __popc(ao[k].x ^ at[k].x) + __popc(ao[k].y ^ at[k].y)
                 + __popc(ao[k].z ^ at[k].z) + __popc(ao[k].w ^ at[k].w);
            sum += __popc(bo[k].x ^ bt[k].x) + __popc(bo[k].y ^ bt[k].y)
                 + __popc(bo[k].z ^ bt[k].z) + __popc(bo[k].w ^ bt[k].w);
        }
    }

    // ---- phase 5: wave(64) reduce, block reduce, publish own 128B line ----
    #pragma unroll
    for (int off = 32; off > 0; off >>= 1)
        sum += __shfl_down(sum, off, 64);
    if ((tid & 63) == 0)
        wsum[tid >> 6] = sum;
    __syncthreads();

    if (tid == 0) {
        unsigned int bsum = 0;
        #pragma unroll
        for (int w = 0; w < THREADS / 64; w++) bsum += wsum[w];
        // bsum <= 1024*512 = 2^19, bit30 marker is safe
        atomicExch(&partials[blockIdx.x * LINE_STRIDE], bsum | PUB_MARKER);
    }

    // ---- collector: block 0 spins on 256 distinct lines, writes mean ----
    if (blockIdx.x == 0) {
        __syncthreads();    // protect wsum reuse below
        unsigned int v = 0;
        if (tid < BLOCKS) {
            do {
                v = atomicAdd(&partials[tid * LINE_STRIDE], 0u);
            } while (!(v & PUB_MARKER));
            v &= ~PUB_MARKER;
        }
        #pragma unroll
        for (int off = 32; off > 0; off >>= 1)
            v += __shfl_down(v, off, 64);
        if ((tid & 63) == 0)
            wsum[tid >> 6] = v;     // waves 4..7 contribute 0
        __syncthreads();
        if (tid == 0) {
            unsigned long long total = 0;
            #pragma unroll
            for (int w = 0; w < THREADS / 64; w++) total += wsum[w];
            out[0] = (float)((double)total / (double)B_SIZE);
        }
    }
}

extern "C" void kernel_launch(void* const* d_in, const int* in_sizes, int n_in,
                              void* d_out, int out_size, void* d_ws, size_t ws_size,
                              hipStream_t stream) {
    const int*   output   = (const int*)d_in[0];    // [B] int32
    const int*   target   = (const int*)d_in[1];    // [B] int32
    const float* codebook = (const float*)d_in[2];  // [1000, 512] float32 (0/1)
    float* out = (float*)d_out;

    unsigned int* partials = (unsigned int*)((char*)d_ws + WS_PART_OFF);
    unsigned int* pflags   = (unsigned int*)((char*)d_ws + WS_FLAG_OFF);
    uint32_t*     packed   = (uint32_t*)((char*)d_ws + WS_PACKED_OFF);

    fused_hamming_kernel<<<BLOCKS, THREADS, 0, stream>>>(
        output, target, codebook, packed, pflags, partials, out);
}

// Round 2
// 96.872 us; speedup vs baseline: 1.0153x; 1.0153x over previous
//
#include <hip/hip_runtime.h>
#include <stdint.h>

#define B_SIZE        262144
#define NUM_CLASSES   1000
#define CODE_LEN      512
#define N_ELEMS       (NUM_CLASSES * CODE_LEN)   // 512000 floats
#define PACKED_WORDS  (NUM_CLASSES * 16)         // 16000 uint32 = 62.5 KB
#define CHUNKS        (NUM_CLASSES * 4)          // 4000 uint4 chunks
#define BLOCKS        256
#define THREADS       512                        // 8 waves/block
#define SAMPLES_PER_BLOCK (B_SIZE / BLOCKS)      // 1024 -> 2 per thread

// ws layout (bytes):
//   [0]      u32 partials[BLOCKS], one per 128B line (stride 32 u32)
//   [32768]  u32 pack-flags[BLOCKS], one per 128B line
//   [65536]  packed codebook, 16000 u32
#define WS_PART_OFF    0
#define WS_FLAG_OFF    32768
#define WS_PACKED_OFF  65536
#define LINE_STRIDE    32             // u32 elements = 128 B
#define PUB_MARKER     0x40000000u    // bit30: poison 0xAAAAAAAA has bit30=0

// Round-1 lesson: spinning with device-scope atomic RMWs (atomicAdd(p,0))
// from 65536 threads serialized at the coherence point -> 44 us barrier.
// Round-2 fix: spin with device-scope atomic LOADS (no ownership, no RMW
// serialization), and only one wave (64 threads) per block polls.
__device__ __forceinline__ unsigned int agent_load(const unsigned int* p) {
    return __hip_atomic_load(p, __ATOMIC_RELAXED, __HIP_MEMORY_SCOPE_AGENT);
}

// Single fused kernel:
//   phase 1: distributed ballot-pack, each block packs 1/256 of the table
//   phase 2: flag barrier — publish via threadfence+atomicExch(marker),
//            wait via one wave of relaxed agent-scope atomic loads
//   phase 3: stage packed table -> LDS (bank-swizzled)
//   phase 4: 2 samples/thread, 16 LDS gathers issued before popcounts
//   phase 5: block reduce -> per-block 128B-line publish -> block 0 collects
// Deadlock-safe without cooperative launch: 64 KB LDS + 512 thr => 2
// blocks/CU capacity, so total capacity (512) >= grid (256): every WG is
// resident before any flag-wait can block.
__global__ __launch_bounds__(THREADS) void fused_hamming_kernel(
        const int* __restrict__ output,
        const int* __restrict__ target,
        const float* __restrict__ codebook,
        uint32_t* __restrict__ packed,
        unsigned int* __restrict__ pflags,
        unsigned int* __restrict__ partials,
        float* __restrict__ out) {
    __shared__ uint4 lds[CHUNKS];               // 64000 B
    __shared__ unsigned int wsum[THREADS / 64]; // 8 waves

    const int tid = threadIdx.x;

    // Prefetch this thread's 4 indices: loads issue now, complete while the
    // pack phase runs.
    int base = blockIdx.x * SAMPLES_PER_BLOCK + tid;
    int o0 = output[base],           t0 = target[base];
    int o1 = output[base + THREADS], t1 = target[base + THREADS];

    // ---- phase 1: distributed pack (grid-strided ballot) ----
    // e = it*131072 + blk*512 + tid; guard is wave-uniform (blocks 232..255
    // are entirely inactive in it=3, never splitting a wave's ballot).
    #pragma unroll
    for (int it = 0; it < 4; it++) {
        int e = it * (BLOCKS * THREADS) + blockIdx.x * THREADS + tid;
        if (e < N_ELEMS) {
            float x = codebook[e];
            unsigned long long m = __ballot(x > 0.5f);
            if ((tid & 31) == 0)
                packed[e >> 5] = (uint32_t)(m >> (tid & 32));
        }
    }
    // Publish: syncthreads drains every wave's stores to this XCD's L2;
    // thread 0's threadfence writes L2 back to the coherence point; then a
    // device-scope atomic sets the bit30-marker flag.
    __syncthreads();
    if (tid == 0) {
        __threadfence();
        atomicExch(&pflags[blockIdx.x * LINE_STRIDE], PUB_MARKER);
    }

    // ---- phase 2: wait for all 256 pack slices (load-only spin) ----
    // One wave polls; thread i watches flags {i, i+64, i+128, i+192}.
    // Poison-proof: poison 0xAAAAAAAA lacks bit30.
    if (tid < 64) {
        #pragma unroll
        for (int j = 0; j < 4; j++) {
            const unsigned int* f = &pflags[(tid + 64 * j) * LINE_STRIDE];
            while (!(agent_load(f) & PUB_MARKER)) {}
        }
    }
    __syncthreads();
    __threadfence();   // acquire: invalidate L1/L2 so plain loads see table

    // ---- phase 3: stage packed table -> LDS with bank swizzle ----
    // chunk k of row r stored at lds[4r + ((k + (r>>2)) & 3)]
    const uint4* pk4 = (const uint4*)packed;
    #pragma unroll
    for (int it = 0; it < 8; it++) {
        int g = tid + THREADS * it;
        if (g < CHUNKS) {
            int r = g >> 2, k = g & 3;
            lds[(r << 2) + ((k + (r >> 2)) & 3)] = pk4[g];
        }
    }
    __syncthreads();

    // ---- phase 4: 2 samples/thread, all 16 gathers issued before popc ----
    unsigned int sum = 0;
    {
        uint4 ao[4], at[4], bo[4], bt[4];
        int so0 = (o0 >> 2) & 3, st0 = (t0 >> 2) & 3;
        int so1 = (o1 >> 2) & 3, st1 = (t1 >> 2) & 3;
        #pragma unroll
        for (int k = 0; k < 4; k++) ao[k] = lds[(o0 << 2) + ((k + so0) & 3)];
        #pragma unroll
        for (int k = 0; k < 4; k++) at[k] = lds[(t0 << 2) + ((k + st0) & 3)];
        #pragma unroll
        for (int k = 0; k < 4; k++) bo[k] = lds[(o1 << 2) + ((k + so1) & 3)];
        #pragma unroll
        for (int k = 0; k < 4; k++) bt[k] = lds[(t1 << 2) + ((k + st1) & 3)];

        #pragma unroll
        for (int k = 0; k < 4; k++) {
            sum += __popc(ao[k].x ^ at[k].x) + __popc(ao[k].y ^ at[k].y)
                 + __popc(ao[k].z ^ at[k].z) + __popc(ao[k].w ^ at[k].w);
            sum += __popc(bo[k].x ^ bt[k].x) + __popc(bo[k].y ^ bt[k].y)
                 + __popc(bo[k].z ^ bt[k].z) + __popc(bo[k].w ^ bt[k].w);
        }
    }

    // ---- phase 5: wave(64) reduce, block reduce, publish own 128B line ----
    #pragma unroll
    for (int off = 32; off > 0; off >>= 1)
        sum += __shfl_down(sum, off, 64);
    if ((tid & 63) == 0)
        wsum[tid >> 6] = sum;
    __syncthreads();

    if (tid == 0) {
        unsigned int bsum = 0;
        #pragma unroll
        for (int w = 0; w < THREADS / 64; w++) bsum += wsum[w];
        // bsum <= 1024*512 = 2^19, bit30 marker is safe
        atomicExch(&partials[blockIdx.x * LINE_STRIDE], bsum | PUB_MARKER);
    }

    // ---- collector: block 0 load-spins on 256 distinct lines, writes mean ----
    if (blockIdx.x == 0) {
        __syncthreads();    // protect wsum reuse below
        unsigned int v = 0;
        if (tid < BLOCKS) {
            do {
                v = agent_load(&partials[tid * LINE_STRIDE]);
            } while (!(v & PUB_MARKER));
            v &= ~PUB_MARKER;
        }
        #pragma unroll
        for (int off = 32; off > 0; off >>= 1)
            v += __shfl_down(v, off, 64);
        if ((tid & 63) == 0)
            wsum[tid >> 6] = v;     // waves 4..7 contribute 0
        __syncthreads();
        if (tid == 0) {
            unsigned long long total = 0;
            #pragma unroll
            for (int w = 0; w < THREADS / 64; w++) total += wsum[w];
            out[0] = (float)((double)total / (double)B_SIZE);
        }
    }
}

extern "C" void kernel_launch(void* const* d_in, const int* in_sizes, int n_in,
                              void* d_out, int out_size, void* d_ws, size_t ws_size,
                              hipStream_t stream) {
    const int*   output   = (const int*)d_in[0];    // [B] int32
    const int*   target   = (const int*)d_in[1];    // [B] int32
    const float* codebook = (const float*)d_in[2];  // [1000, 512] float32 (0/1)
    float* out = (float*)d_out;

    unsigned int* partials = (unsigned int*)((char*)d_ws + WS_PART_OFF);
    unsigned int* pflags   = (unsigned int*)((char*)d_ws + WS_FLAG_OFF);
    uint32_t*     packed   = (uint32_t*)((char*)d_ws + WS_PACKED_OFF);

    fused_hamming_kernel<<<BLOCKS, THREADS, 0, stream>>>(
        output, target, codebook, packed, pflags, partials, out);
}

// Round 3
// 67.330 us; speedup vs baseline: 1.4608x; 1.4388x over previous
//
#include <hip/hip_runtime.h>
#include <stdint.h>

#define B_SIZE        262144
#define NUM_CLASSES   1000
#define CODE_LEN      512
#define N_ELEMS       (NUM_CLASSES * CODE_LEN)   // 512000 floats
#define PACKED_WORDS  (NUM_CLASSES * 16)         // 16000 uint32 = 62.5 KB
#define CHUNKS        (NUM_CLASSES * 4)          // 4000 uint4 chunks
#define BLOCKS        256
#define THREADS       512                        // 8 waves/block
#define SAMPLES_PER_BLOCK (B_SIZE / BLOCKS)      // 1024 -> 2 per thread

// ws layout (bytes):
//   [0]      u32 partials[BLOCKS], one per 128B line (stride 32 u32)
//   [32768]  u32 pack-flags[BLOCKS], one per 128B line
//   [65536]  packed codebook, 16000 u32
#define WS_PART_OFF    0
#define WS_FLAG_OFF    32768
#define WS_PACKED_OFF  65536
#define LINE_STRIDE    32             // u32 elements = 128 B
#define PUB_MARKER     0x40000000u    // bit30: poison 0xAAAAAAAA has bit30=0

// Round-1 lesson: RMW-spin vs load-spin made ZERO difference (44.3 vs 44.2us)
// -> the spin was never the cost.
// Round-2 lesson: the fences were. __threadfence() in all 512 threads emitted
// 2048 buffer_inv sc1 (each wiping its XCD's 4MiB L2 while neighbor blocks
// streamed staging reads through it) + 256 buffer_wbl2 sc1 tag-walks.
// Round-3 fix: FENCE-FREE handoff. All cross-block data moves through the
// coherence point (MALL) via relaxed agent-scope atomic ops (sc0 sc1 bypass):
//   - packers publish table words with bypass STORES (write-through)
//   - readers stage with bypass LOADS (no cached copy -> no invalidate needed)
//   - flags/partials are single-word atomicExch+load protocols (flag and data
//     in one word -> no ordering fence required)
// Not a single cache-maintenance instruction in the binary.
__device__ __forceinline__ unsigned int bypass_load(const unsigned int* p) {
    return __hip_atomic_load(p, __ATOMIC_RELAXED, __HIP_MEMORY_SCOPE_AGENT);
}
__device__ __forceinline__ void bypass_store(unsigned int* p, unsigned int v) {
    __hip_atomic_store(p, v, __ATOMIC_RELAXED, __HIP_MEMORY_SCOPE_AGENT);
}

// Deadlock-safe without cooperative launch: 64 KB LDS + 512 thr => 2
// blocks/CU capacity, so total capacity (512) >= grid (256): every WG is
// resident before any flag-wait can block.
__global__ __launch_bounds__(THREADS) void fused_hamming_kernel(
        const int* __restrict__ output,
        const int* __restrict__ target,
        const float* __restrict__ codebook,
        uint32_t* __restrict__ packed,
        unsigned int* __restrict__ pflags,
        unsigned int* __restrict__ partials,
        float* __restrict__ out) {
    __shared__ uint4 lds[CHUNKS];               // 64000 B
    __shared__ unsigned int wsum[THREADS / 64]; // 8 waves

    const int tid = threadIdx.x;

    // Prefetch this thread's 4 indices (normal cached loads; inputs are
    // read-only and handed off by stream order).
    int base = blockIdx.x * SAMPLES_PER_BLOCK + tid;
    int o0 = output[base],           t0 = target[base];
    int o1 = output[base + THREADS], t1 = target[base + THREADS];

    // ---- phase 1: distributed pack, published via bypass stores ----
    // e = it*131072 + blk*512 + tid; guard is wave-uniform (the active/
    // inactive boundary at 512000 = 232 blocks into it=3 is block-aligned).
    #pragma unroll
    for (int it = 0; it < 4; it++) {
        int e = it * (BLOCKS * THREADS) + blockIdx.x * THREADS + tid;
        if (e < N_ELEMS) {
            float x = codebook[e];
            unsigned long long m = __ballot(x > 0.5f);
            if ((tid & 31) == 0)
                bypass_store(&packed[e >> 5], (uint32_t)(m >> (tid & 32)));
        }
    }
    // syncthreads drains each wave's vmcnt -> all bypass stores have reached
    // the coherence point. Then one coherent RMW sets the bit30-marker flag.
    __syncthreads();
    if (tid == 0)
        atomicExch(&pflags[blockIdx.x * LINE_STRIDE], PUB_MARKER);

    // ---- phase 2: wait for all 256 pack slices (load-only spin, no fence) --
    // One wave polls; thread i watches flags {i, i+64, i+128, i+192}.
    // Poison-proof: poison 0xAAAAAAAA lacks bit30.
    if (tid < 64) {
        #pragma unroll
        for (int j = 0; j < 4; j++) {
            const unsigned int* f = &pflags[(tid + 64 * j) * LINE_STRIDE];
            while (!(bypass_load(f) & PUB_MARKER)) {}
        }
    }
    __syncthreads();

    // ---- phase 3: stage table -> LDS via bypass loads (bank-swizzled) ----
    // Reads go straight to the coherence point where the published words
    // live; no cached copies exist so no invalidate is needed.
    // chunk k of row r stored at lds[4r + ((k + (r>>2)) & 3)]
    #pragma unroll
    for (int it = 0; it < 8; it++) {
        int g = tid + THREADS * it;
        if (g < CHUNKS) {
            int r = g >> 2, k = g & 3;
            const unsigned int* src = &packed[g << 2];
            uint4 c;
            c.x = bypass_load(src + 0);
            c.y = bypass_load(src + 1);
            c.z = bypass_load(src + 2);
            c.w = bypass_load(src + 3);
            lds[(r << 2) + ((k + (r >> 2)) & 3)] = c;
        }
    }
    __syncthreads();

    // ---- phase 4: 2 samples/thread, all 16 gathers issued before popc ----
    unsigned int sum = 0;
    {
        uint4 ao[4], at[4], bo[4], bt[4];
        int so0 = (o0 >> 2) & 3, st0 = (t0 >> 2) & 3;
        int so1 = (o1 >> 2) & 3, st1 = (t1 >> 2) & 3;
        #pragma unroll
        for (int k = 0; k < 4; k++) ao[k] = lds[(o0 << 2) + ((k + so0) & 3)];
        #pragma unroll
        for (int k = 0; k < 4; k++) at[k] = lds[(t0 << 2) + ((k + st0) & 3)];
        #pragma unroll
        for (int k = 0; k < 4; k++) bo[k] = lds[(o1 << 2) + ((k + so1) & 3)];
        #pragma unroll
        for (int k = 0; k < 4; k++) bt[k] = lds[(t1 << 2) + ((k + st1) & 3)];

        #pragma unroll
        for (int k = 0; k < 4; k++) {
            sum += __popc(ao[k].x ^ at[k].x) + __popc(ao[k].y ^ at[k].y)
                 + __popc(ao[k].z ^ at[k].z) + __popc(ao[k].w ^ at[k].w);
            sum += __popc(bo[k].x ^ bt[k].x) + __popc(bo[k].y ^ bt[k].y)
                 + __popc(bo[k].z ^ bt[k].z) + __popc(bo[k].w ^ bt[k].w);
        }
    }

    // ---- phase 5: wave(64) reduce, block reduce, publish own 128B line ----
    #pragma unroll
    for (int off = 32; off > 0; off >>= 1)
        sum += __shfl_down(sum, off, 64);
    if ((tid & 63) == 0)
        wsum[tid >> 6] = sum;
    __syncthreads();

    if (tid == 0) {
        unsigned int bsum = 0;
        #pragma unroll
        for (int w = 0; w < THREADS / 64; w++) bsum += wsum[w];
        // bsum <= 1024*512 = 2^19, bit30 marker is safe; flag+data share one
        // word -> transfer happens through the atomic itself, fence-free.
        atomicExch(&partials[blockIdx.x * LINE_STRIDE], bsum | PUB_MARKER);
    }

    // ---- collector: block 0 load-spins on 256 distinct lines, writes mean --
    if (blockIdx.x == 0) {
        __syncthreads();    // protect wsum reuse below
        unsigned int v = 0;
        if (tid < BLOCKS) {
            do {
                v = bypass_load(&partials[tid * LINE_STRIDE]);
            } while (!(v & PUB_MARKER));
            v &= ~PUB_MARKER;
        }
        #pragma unroll
        for (int off = 32; off > 0; off >>= 1)
            v += __shfl_down(v, off, 64);
        if ((tid & 63) == 0)
            wsum[tid >> 6] = v;     // waves 4..7 contribute 0
        __syncthreads();
        if (tid == 0) {
            unsigned long long total = 0;
            #pragma unroll
            for (int w = 0; w < THREADS / 64; w++) total += wsum[w];
            out[0] = (float)((double)total / (double)B_SIZE);
        }
    }
}

extern "C" void kernel_launch(void* const* d_in, const int* in_sizes, int n_in,
                              void* d_out, int out_size, void* d_ws, size_t ws_size,
                              hipStream_t stream) {
    const int*   output   = (const int*)d_in[0];    // [B] int32
    const int*   target   = (const int*)d_in[1];    // [B] int32
    const float* codebook = (const float*)d_in[2];  // [1000, 512] float32 (0/1)
    float* out = (float*)d_out;

    unsigned int* partials = (unsigned int*)((char*)d_ws + WS_PART_OFF);
    unsigned int* pflags   = (unsigned int*)((char*)d_ws + WS_FLAG_OFF);
    uint32_t*     packed   = (uint32_t*)((char*)d_ws + WS_PACKED_OFF);

    fused_hamming_kernel<<<BLOCKS, THREADS, 0, stream>>>(
        output, target, codebook, packed, pflags, partials, out);
}

// Round 4
// 64.162 us; speedup vs baseline: 1.5329x; 1.0494x over previous
//
#include <hip/hip_runtime.h>
#include <stdint.h>

#define B_SIZE        262144
#define NUM_CLASSES   1000
#define CODE_LEN      512
#define N_ELEMS       (NUM_CLASSES * CODE_LEN)   // 512000 floats
#define PACKED_WORDS  (NUM_CLASSES * 16)         // 16000 uint32 = 62.5 KB
#define CHUNKS        (NUM_CLASSES * 4)          // 4000 uint4 chunks
#define BLOCKS        256
#define THREADS       512                        // 8 waves/block
#define SAMPLES_PER_BLOCK (B_SIZE / BLOCKS)      // 1024 -> 2 per thread

// ws layout (bytes):
//   [0]      u32 partials[BLOCKS], one per 128B line (stride 32 u32)
//   [32768]  u32 pack-flags[BLOCKS], one per 128B line
//   [65536]  packed codebook, 16000 u32
#define WS_PART_OFF    0
#define WS_FLAG_OFF    32768
#define WS_PACKED_OFF  65536
#define LINE_STRIDE    32             // u32 elements = 128 B
#define PUB_MARKER     0x40000000u    // bit30: poison 0xAAAAAAAA has bit30=0

// R1 lesson: RMW-spin vs load-spin: no difference -> spin never the cost.
// R2 lesson: __threadfence() (2304 wave-level buffer_wbl2+buffer_inv
//            serializing at 8 L2s) was the 30us cost. Fence-free now.
// R3 lesson: fence-free handoff works (44 -> ~15us), but staging via
//            4-byte bypass loads (global_load_dword sc0 sc1, ~4 in flight
//            per wave) is latency-bound at the coherence point.
// R4 fix: 16-byte bypass staging via inline asm global_load_dwordx4 sc0 sc1,
//         issued 8-deep per wave, single vmcnt(0) drain, then LDS writes.
__device__ __forceinline__ unsigned int bypass_load(const unsigned int* p) {
    return __hip_atomic_load(p, __ATOMIC_RELAXED, __HIP_MEMORY_SCOPE_AGENT);
}
__device__ __forceinline__ void bypass_store(unsigned int* p, unsigned int v) {
    __hip_atomic_store(p, v, __ATOMIC_RELAXED, __HIP_MEMORY_SCOPE_AGENT);
}

// Deadlock-safe without cooperative launch: 64 KB LDS + 512 thr => 2
// blocks/CU capacity, so total capacity (512) >= grid (256): every WG is
// resident before any flag-wait can block.
__global__ __launch_bounds__(THREADS) void fused_hamming_kernel(
        const int* __restrict__ output,
        const int* __restrict__ target,
        const float* __restrict__ codebook,
        uint32_t* __restrict__ packed,
        unsigned int* __restrict__ pflags,
        unsigned int* __restrict__ partials,
        float* __restrict__ out) {
    __shared__ uint4 lds[CHUNKS];               // 64000 B
    __shared__ unsigned int wsum[THREADS / 64]; // 8 waves

    const int tid = threadIdx.x;

    // Prefetch this thread's 4 indices (normal cached loads; inputs are
    // read-only and handed off by stream order).
    int base = blockIdx.x * SAMPLES_PER_BLOCK + tid;
    int o0 = output[base],           t0 = target[base];
    int o1 = output[base + THREADS], t1 = target[base + THREADS];

    // ---- phase 1: distributed pack, published via bypass stores ----
    // e = it*131072 + blk*512 + tid; block b packs rows {b, 256+b, 512+b,
    // 768+b}; guard is wave-uniform (active/inactive boundary block-aligned).
    #pragma unroll
    for (int it = 0; it < 4; it++) {
        int e = it * (BLOCKS * THREADS) + blockIdx.x * THREADS + tid;
        if (e < N_ELEMS) {
            float x = codebook[e];
            unsigned long long m = __ballot(x > 0.5f);
            if ((tid & 31) == 0)
                bypass_store(&packed[e >> 5], (uint32_t)(m >> (tid & 32)));
        }
    }
    // syncthreads drains each wave's vmcnt -> all bypass stores have reached
    // the coherence point. Then one coherent RMW sets the bit30-marker flag.
    __syncthreads();
    if (tid == 0)
        atomicExch(&pflags[blockIdx.x * LINE_STRIDE], PUB_MARKER);

    // ---- phase 2: wait for all 256 pack slices (load-only spin, no fence) --
    // One wave polls; thread i watches flags {i, i+64, i+128, i+192}.
    // Poison-proof: poison 0xAAAAAAAA lacks bit30.
    if (tid < 64) {
        #pragma unroll
        for (int j = 0; j < 4; j++) {
            const unsigned int* f = &pflags[(tid + 64 * j) * LINE_STRIDE];
            while (!(bypass_load(f) & PUB_MARKER)) {}
        }
    }
    __syncthreads();

    // ---- phase 3: stage table -> LDS via 16B bypass loads (bank-swizzled) --
    // Issue all 8 dwordx4 sc0 sc1 loads (8 outstanding per wave), drain once,
    // then write LDS. sched_barrier(0) after the manual waitcnt per rule #18.
    // chunk k of row r stored at lds[4r + ((k + (r>>2)) & 3)]
    {
        uint4 c[8];
        #pragma unroll
        for (int it = 0; it < 8; it++) {
            int g = tid + THREADS * it;
            if (g < CHUNKS) {
                const uint32_t* src = &packed[(size_t)g << 2];  // 16B aligned
                asm volatile("global_load_dwordx4 %0, %1, off sc0 sc1"
                             : "=v"(c[it]) : "v"(src) : "memory");
            }
        }
        asm volatile("s_waitcnt vmcnt(0)" ::: "memory");
        __builtin_amdgcn_sched_barrier(0);
        #pragma unroll
        for (int it = 0; it < 8; it++) {
            int g = tid + THREADS * it;
            if (g < CHUNKS) {
                int r = g >> 2, k = g & 3;
                lds[(r << 2) + ((k + (r >> 2)) & 3)] = c[it];
            }
        }
    }
    __syncthreads();

    // ---- phase 4: 2 samples/thread, all 16 gathers issued before popc ----
    unsigned int sum = 0;
    {
        uint4 ao[4], at[4], bo[4], bt[4];
        int so0 = (o0 >> 2) & 3, st0 = (t0 >> 2) & 3;
        int so1 = (o1 >> 2) & 3, st1 = (t1 >> 2) & 3;
        #pragma unroll
        for (int k = 0; k < 4; k++) ao[k] = lds[(o0 << 2) + ((k + so0) & 3)];
        #pragma unroll
        for (int k = 0; k < 4; k++) at[k] = lds[(t0 << 2) + ((k + st0) & 3)];
        #pragma unroll
        for (int k = 0; k < 4; k++) bo[k] = lds[(o1 << 2) + ((k + so1) & 3)];
        #pragma unroll
        for (int k = 0; k < 4; k++) bt[k] = lds[(t1 << 2) + ((k + st1) & 3)];

        #pragma unroll
        for (int k = 0; k < 4; k++) {
            sum += __popc(ao[k].x ^ at[k].x) + __popc(ao[k].y ^ at[k].y)
                 + __popc(ao[k].z ^ at[k].z) + __popc(ao[k].w ^ at[k].w);
            sum += __popc(bo[k].x ^ bt[k].x) + __popc(bo[k].y ^ bt[k].y)
                 + __popc(bo[k].z ^ bt[k].z) + __popc(bo[k].w ^ bt[k].w);
        }
    }

    // ---- phase 5: wave(64) reduce, block reduce, publish own 128B line ----
    #pragma unroll
    for (int off = 32; off > 0; off >>= 1)
        sum += __shfl_down(sum, off, 64);
    if ((tid & 63) == 0)
        wsum[tid >> 6] = sum;
    __syncthreads();

    if (tid == 0) {
        unsigned int bsum = 0;
        #pragma unroll
        for (int w = 0; w < THREADS / 64; w++) bsum += wsum[w];
        // bsum <= 1024*512 = 2^19, bit30 marker is safe; flag+data share one
        // word -> transfer happens through the atomic itself, fence-free.
        atomicExch(&partials[blockIdx.x * LINE_STRIDE], bsum | PUB_MARKER);
    }

    // ---- collector: block 0 load-spins on 256 distinct lines, writes mean --
    if (blockIdx.x == 0) {
        __syncthreads();    // protect wsum reuse below
        unsigned int v = 0;
        if (tid < BLOCKS) {
            do {
                v = bypass_load(&partials[tid * LINE_STRIDE]);
            } while (!(v & PUB_MARKER));
            v &= ~PUB_MARKER;
        }
        #pragma unroll
        for (int off = 32; off > 0; off >>= 1)
            v += __shfl_down(v, off, 64);
        if ((tid & 63) == 0)
            wsum[tid >> 6] = v;     // waves 4..7 contribute 0
        __syncthreads();
        if (tid == 0) {
            unsigned long long total = 0;
            #pragma unroll
            for (int w = 0; w < THREADS / 64; w++) total += wsum[w];
            out[0] = (float)((double)total / (double)B_SIZE);
        }
    }
}

extern "C" void kernel_launch(void* const* d_in, const int* in_sizes, int n_in,
                              void* d_out, int out_size, void* d_ws, size_t ws_size,
                              hipStream_t stream) {
    const int*   output   = (const int*)d_in[0];    // [B] int32
    const int*   target   = (const int*)d_in[1];    // [B] int32
    const float* codebook = (const float*)d_in[2];  // [1000, 512] float32 (0/1)
    float* out = (float*)d_out;

    unsigned int* partials = (unsigned int*)((char*)d_ws + WS_PART_OFF);
    unsigned int* pflags   = (unsigned int*)((char*)d_ws + WS_FLAG_OFF);
    uint32_t*     packed   = (uint32_t*)((char*)d_ws + WS_PACKED_OFF);

    fused_hamming_kernel<<<BLOCKS, THREADS, 0, stream>>>(
        output, target, codebook, packed, pflags, partials, out);
}